// Round 1
// baseline (212.230 us; speedup 1.0000x reference)
//
#include <hip/hip_runtime.h>
#include <cstddef>

#define BSZ   2
#define NN    384
#define DATOM 512
#define DPAIR 128
#define DHID  32

// ---------------------------------------------------------------------------
// Workspace layout (floats):
//   abuf [BSZ][NN][32]        offset 0       (24576)   'a' half of ab
//   bbT  [BSZ][32][NN]        offset 24576   (24576)   'b' half, transposed
//   T    [BSZ][NN][128][32]   offset 49152   (3145728) T[b,i,p,y]
// total ~12.8 MB
// ---------------------------------------------------------------------------

// Kernel A: ab = (m @ W_in^T + b_in) * op_mask; split into abuf / bbT.
// grid 192 x 256: block handles 4 rows (b*NN+n).
__global__ __launch_bounds__(256) void k_ab(
    const float* __restrict__ m, const float* __restrict__ op_mask,
    const float* __restrict__ W_in, const float* __restrict__ b_in,
    float* __restrict__ abuf, float* __restrict__ bbT)
{
    __shared__ __align__(16) float mrow[4 * DATOM];
    const int t  = threadIdx.x;
    const int r0 = blockIdx.x * 4;

    const float4* msrc = (const float4*)(m + (size_t)r0 * DATOM);
    float4* mdst = (float4*)mrow;
    mdst[t]       = msrc[t];
    mdst[t + 256] = msrc[t + 256];
    __syncthreads();

    const int h    = t & 63;
    const int rloc = t >> 6;
    const int row  = r0 + rloc;

    const float4* wrow = (const float4*)(W_in + (size_t)h * DATOM);
    const float4* ml   = (const float4*)(mrow + rloc * DATOM);
    float acc = 0.f;
#pragma unroll 16
    for (int d4 = 0; d4 < DATOM / 4; ++d4) {
        const float4 w  = wrow[d4];
        const float4 mm = ml[d4];
        acc += w.x * mm.x + w.y * mm.y + w.z * mm.z + w.w * mm.w;
    }
    const float val = (acc + b_in[h]) * op_mask[row];
    const int b = row / NN;
    const int n = row - b * NN;
    if (h < DHID)
        abuf[(size_t)row * DHID + h] = val;
    else
        bbT[((size_t)b * DHID + (h - DHID)) * NN + n] = val;
}

// Kernel B: T[b,i,p,y] = sum_x a[b,i,x] * W_out[p, x*32+y]
// grid 192 x 256: block = (i-group of 8 rows) x (p-half of 64).
__global__ __launch_bounds__(256) void k_T(
    const float* __restrict__ abuf, const float* __restrict__ W_out,
    float* __restrict__ T)
{
    __shared__ __align__(16) float alds[8 * DHID];
    const int t    = threadIdx.x;
    const int ig   = blockIdx.x >> 1;   // 0..95
    const int half = blockIdx.x & 1;    // p offset 0 / 64
    const int r0   = ig * 8;            // flat (b*NN+i) base

    alds[t & 255] = abuf[(size_t)r0 * DHID + (t & 255)];
    __syncthreads();

    const int y  = t & 31;
    const int pg = t >> 5;              // 0..7
#pragma unroll
    for (int k = 0; k < 2; ++k) {
        float acc[4][8];
#pragma unroll
        for (int c = 0; c < 4; ++c)
#pragma unroll
            for (int i = 0; i < 8; ++i) acc[c][i] = 0.f;

#pragma unroll
        for (int xc = 0; xc < 8; ++xc) {
            float4 a4[8];
#pragma unroll
            for (int i = 0; i < 8; ++i)
                a4[i] = *(const float4*)&alds[i * DHID + xc * 4];
#pragma unroll
            for (int xi = 0; xi < 4; ++xi) {
                const int x = xc * 4 + xi;
                float w[4];
#pragma unroll
                for (int c = 0; c < 4; ++c) {
                    const int p = pg + 8 * (4 * k + c) + 64 * half;
                    w[c] = W_out[(size_t)p * (DHID * DHID) + x * DHID + y];
                }
#pragma unroll
                for (int i = 0; i < 8; ++i) {
                    const float av = (xi == 0) ? a4[i].x
                                   : (xi == 1) ? a4[i].y
                                   : (xi == 2) ? a4[i].z : a4[i].w;
#pragma unroll
                    for (int c = 0; c < 4; ++c) acc[c][i] += av * w[c];
                }
            }
        }
#pragma unroll
        for (int c = 0; c < 4; ++c) {
            const int p = pg + 8 * (4 * k + c) + 64 * half;
#pragma unroll
            for (int i = 0; i < 8; ++i)
                T[(((size_t)(r0 + i)) * DPAIR + p) * DHID + y] = acc[c][i];
        }
    }
}

// Kernel C: z[b,i,j,p] = (sum_y bb[b,j,y]*T[b,i,p,y] + b_out[p]) * op_norm
// grid 768 x 256: block = one (b,i); GEMM M=384(j) N=128(p) K=32(y).
// Tl: [y][p] chunked — p-chunk (8 floats) at stride 12 => 2-way banks (free).
#define TL_STRIDE 196   // 16 chunks * 12 + pad; 196%32=4 spreads staging rows
#define BL_STRIDE 132

__global__ __launch_bounds__(256, 3) void k_main(
    const float* __restrict__ T, const float* __restrict__ bbT,
    const float* __restrict__ b_out, const float* __restrict__ op_norm,
    float* __restrict__ out)
{
    __shared__ __align__(16) float Tl[32 * TL_STRIDE];
    __shared__ __align__(16) float Bl[32 * BL_STRIDE];
    const int t   = threadIdx.x;
    const int blk = blockIdx.x;          // b*NN + i
    const int b   = blk / NN;

    // stage T_i: global [p][y] (coalesced) -> Tl[y][chunk(p)]
    const float4* Tg4 = (const float4*)(T + (size_t)blk * (DPAIR * DHID));
#pragma unroll
    for (int q = 0; q < 4; ++q) {
        const int f4 = t + q * 256;      // 0..1023
        const int p  = f4 >> 3;
        const int y4 = (f4 & 7) * 4;
        const float4 v = Tg4[f4];
        const int col = (p >> 3) * 12 + (p & 7);
        Tl[(y4 + 0) * TL_STRIDE + col] = v.x;
        Tl[(y4 + 1) * TL_STRIDE + col] = v.y;
        Tl[(y4 + 2) * TL_STRIDE + col] = v.z;
        Tl[(y4 + 3) * TL_STRIDE + col] = v.w;
    }

    const float onorm = op_norm[0];
    const int tp = t & 15;               // p-group: p0 = tp*8
    const int tj = t >> 4;               // j-group: j0 = tj*8
    float bo[8];
#pragma unroll
    for (int q = 0; q < 8; ++q) bo[q] = b_out[tp * 8 + q];

    const float* Bgb = bbT + (size_t)b * DHID * NN;

    for (int jt = 0; jt < 3; ++jt) {
        __syncthreads();                 // Tl/Bl write->read & reuse fence
#pragma unroll
        for (int q = 0; q < 4; ++q) {
            const int f4 = t + q * 256;  // 0..1023 over [32][32 float4]
            const int y  = f4 >> 5;
            const int j4 = (f4 & 31) * 4;
            const float4 v = *(const float4*)(Bgb + (size_t)y * NN + jt * 128 + j4);
            *(float4*)&Bl[y * BL_STRIDE + j4] = v;
        }
        __syncthreads();

        float acc[8][8];
#pragma unroll
        for (int jj = 0; jj < 8; ++jj)
#pragma unroll
            for (int pp = 0; pp < 8; ++pp) acc[jj][pp] = 0.f;

#pragma unroll 4
        for (int y = 0; y < 32; ++y) {
            const float* trow = &Tl[y * TL_STRIDE + tp * 12];
            const float4 t0 = *(const float4*)(trow);
            const float4 t1 = *(const float4*)(trow + 4);
            const float* brow = &Bl[y * BL_STRIDE + tj * 8];
            const float4 b0 = *(const float4*)(brow);
            const float4 b1 = *(const float4*)(brow + 4);
            const float tv[8] = {t0.x, t0.y, t0.z, t0.w, t1.x, t1.y, t1.z, t1.w};
            const float bv[8] = {b0.x, b0.y, b0.z, b0.w, b1.x, b1.y, b1.z, b1.w};
#pragma unroll
            for (int jj = 0; jj < 8; ++jj)
#pragma unroll
                for (int pp = 0; pp < 8; ++pp)
                    acc[jj][pp] += bv[jj] * tv[pp];
        }

        float* orow = out + (((size_t)blk * NN) + jt * 128 + tj * 8) * DPAIR + tp * 8;
#pragma unroll
        for (int jj = 0; jj < 8; ++jj) {
            float4 o0, o1;
            o0.x = (acc[jj][0] + bo[0]) * onorm;
            o0.y = (acc[jj][1] + bo[1]) * onorm;
            o0.z = (acc[jj][2] + bo[2]) * onorm;
            o0.w = (acc[jj][3] + bo[3]) * onorm;
            o1.x = (acc[jj][4] + bo[4]) * onorm;
            o1.y = (acc[jj][5] + bo[5]) * onorm;
            o1.z = (acc[jj][6] + bo[6]) * onorm;
            o1.w = (acc[jj][7] + bo[7]) * onorm;
            *(float4*)(orow + (size_t)jj * DPAIR)     = o0;
            *(float4*)(orow + (size_t)jj * DPAIR + 4) = o1;
        }
    }
}

extern "C" void kernel_launch(void* const* d_in, const int* in_sizes, int n_in,
                              void* d_out, int out_size, void* d_ws, size_t ws_size,
                              hipStream_t stream)
{
    const float* m       = (const float*)d_in[0];
    const float* op_mask = (const float*)d_in[1];
    const float* op_norm = (const float*)d_in[2];
    const float* W_in    = (const float*)d_in[3];
    const float* b_in    = (const float*)d_in[4];
    const float* W_out   = (const float*)d_in[5];
    const float* b_out   = (const float*)d_in[6];
    float* out = (float*)d_out;

    float* ws   = (float*)d_ws;
    float* abuf = ws;                  // 24576 floats
    float* bbT  = ws + 24576;          // 24576 floats
    float* T    = ws + 49152;          // 3145728 floats

    hipLaunchKernelGGL(k_ab,   dim3(BSZ * NN / 4),     dim3(256), 0, stream,
                       m, op_mask, W_in, b_in, abuf, bbT);
    hipLaunchKernelGGL(k_T,    dim3((BSZ * NN / 8) * 2), dim3(256), 0, stream,
                       abuf, W_out, T);
    hipLaunchKernelGGL(k_main, dim3(BSZ * NN),         dim3(256), 0, stream,
                       T, bbT, b_out, op_norm, out);
}